// Round 20
// baseline (157.272 us; speedup 1.0000x reference)
//
#include <hip/hip_runtime.h>

typedef __attribute__((ext_vector_type(8))) short short8;
typedef __attribute__((ext_vector_type(8))) unsigned short ushort8;
typedef __attribute__((ext_vector_type(4))) unsigned short ushort4v;
typedef __attribute__((ext_vector_type(4))) float f32x4;
typedef __attribute__((ext_vector_type(16))) float f32x16;

#define DEV static __device__ __forceinline__

DEV unsigned short f2bf(float f) {
  unsigned u = __builtin_bit_cast(unsigned, f);
  u += 0x7fffu + ((u >> 16) & 1u);
  return (unsigned short)(u >> 16);
}

DEV float bf2f(unsigned short u) {
  return __builtin_bit_cast(float, (unsigned)u << 16);
}

DEV void gload_lds16(const void* g, void* l) {
  __builtin_amdgcn_global_load_lds((__attribute__((address_space(1))) void*)g,
                                   (__attribute__((address_space(3))) void*)l,
                                   16, 0, 0);
}

DEV unsigned cvtpk(float lo, float hi) {
  unsigned u;
  asm("v_cvt_pk_bf16_f32 %0, %1, %2" : "=v"(u) : "v"(lo), "v"(hi));
  return u;
}

// v_permlane32_swap_b32 a, b:  lane<32: a'=own a, b'=partner(l+32)'s a;
// lane>=32: a'=partner's b, b'=own b.
DEV void pl32(unsigned& a, unsigned& b) {
  asm("v_permlane32_swap_b32 %0, %1" : "+v"(a), "+v"(b));
}

DEV short8 pack4(unsigned a, unsigned b, unsigned c, unsigned d) {
  int4 t = make_int4((int)a, (int)b, (int)c, (int)d);
  return __builtin_bit_cast(short8, t);
}

// ---------------------------------------------------------------------------
// fused fp32 -> bf16 convert for all 7 regions + bias pack, ONE launch.
// ---------------------------------------------------------------------------
__global__ __launch_bounds__(256) void cvt_all_k(
    const float4* __restrict__ wq, const float4* __restrict__ wk,
    const float4* __restrict__ wv, const float4* __restrict__ wo,
    const float4* __restrict__ w1, const float4* __restrict__ w2,
    const float4* __restrict__ x, ushort4v* __restrict__ wqkv,
    ushort4v* __restrict__ wob, ushort4v* __restrict__ w1b,
    ushort4v* __restrict__ w2b, ushort4v* __restrict__ xb,
    const float* __restrict__ bq, const float* __restrict__ bk,
    const float* __restrict__ bv, float* __restrict__ bo) {
  const int i = threadIdx.x;
  const int b = blockIdx.x;
  if (b >= 7168) {  // bias pack
#pragma unroll
    for (int j = 0; j < 2; j++) {
      const int idx = j * 256 + i;
      bo[idx] = bq[idx];
      bo[512 + idx] = bk[idx];
      bo[1024 + idx] = bv[idx];
    }
    return;
  }
  const float4* s;
  ushort4v* d;
  size_t u;
  if (b < 256)       { s = wq; d = wqkv;          u = (size_t)b * 256 + i; }
  else if (b < 512)  { s = wk; d = wqkv + 65536;  u = (size_t)(b - 256) * 256 + i; }
  else if (b < 768)  { s = wv; d = wqkv + 131072; u = (size_t)(b - 512) * 256 + i; }
  else if (b < 1024) { s = wo; d = wob;           u = (size_t)(b - 768) * 256 + i; }
  else if (b < 2048) { s = w1; d = w1b;           u = (size_t)(b - 1024) * 256 + i; }
  else if (b < 3072) { s = w2; d = w2b;           u = (size_t)(b - 2048) * 256 + i; }
  else               { s = x;  d = xb;            u = (size_t)(b - 3072) * 256 + i; }
  float4 v = s[u];
  ushort4v o = { f2bf(v.x), f2bf(v.y), f2bf(v.z), f2bf(v.w) };
  d[u] = o;
}

// ---------------------------------------------------------------------------
// GEMM 128x128, BK=64, 4 waves. Source-pre-swizzled staging.
// EPI 0: QKV scatter. Q (scaled by log2e/8) -> [bh][s][d], K -> [bh][s][d],
//        V -> TRANSPOSED [bh][d][s] via LDS-transpose (coalesced stores).
// ---------------------------------------------------------------------------
template <int EPI>
__global__ __launch_bounds__(256) void gemm_bt(
    const unsigned short* __restrict__ A, const unsigned short* __restrict__ Bw,
    const float* __restrict__ bias, int M, int N, int K,
    unsigned short* __restrict__ outb, float* __restrict__ outf,
    const unsigned short* __restrict__ residb) {
  __shared__ __align__(16) unsigned short As[128 * 64];
  __shared__ __align__(16) unsigned short Bs[128 * 64];
  const int tid = threadIdx.x;
  const int lane = tid & 63;
  const int wv = tid >> 6;
  const int wr = wv >> 1, wc = wv & 1;
  const int lrow = lane & 15, lgrp = lane >> 4;
  const int bm = blockIdx.x * 128;
  const int bn = blockIdx.y * 128;

  f32x4 acc[4][4];
#pragma unroll
  for (int m = 0; m < 4; m++)
#pragma unroll
    for (int n = 0; n < 4; n++) acc[m][n] = (f32x4){0.f, 0.f, 0.f, 0.f};

  for (int k0 = 0; k0 < K; k0 += 64) {
    __syncthreads();
#pragma unroll
    for (int i = 0; i < 4; i++) {
      const int sb = wv * 64 + i * 256;   // wave-uniform LDS slot base
      const int slot = sb + lane;
      const int row = slot >> 3;
      const int cc = (slot & 7) ^ (row & 7);   // pre-swizzled source chunk
      gload_lds16(A + (size_t)(bm + row) * K + k0 + cc * 8, &As[sb * 8]);
      gload_lds16(Bw + (size_t)(bn + row) * K + k0 + cc * 8, &Bs[sb * 8]);
    }
    __syncthreads();

#pragma unroll
    for (int kk = 0; kk < 2; kk++) {
      short8 af[4], bfr[4];
#pragma unroll
      for (int m = 0; m < 4; m++) {
        const int row = wr * 64 + m * 16 + lrow;
        af[m] = *(const short8*)&As[row * 64 + (((lgrp + 4 * kk) ^ (row & 7)) * 8)];
      }
#pragma unroll
      for (int n = 0; n < 4; n++) {
        const int row = wc * 64 + n * 16 + lrow;
        bfr[n] = *(const short8*)&Bs[row * 64 + (((lgrp + 4 * kk) ^ (row & 7)) * 8)];
      }
#pragma unroll
      for (int m = 0; m < 4; m++)
#pragma unroll
        for (int n = 0; n < 4; n++)
          acc[m][n] = __builtin_amdgcn_mfma_f32_16x16x32_bf16(af[m], bfr[n], acc[m][n], 0, 0, 0);
    }
  }

  if constexpr (EPI == 0) {
    const int proj = bn >> 9;  // block-uniform: 0=Q, 1=K, 2=V
    if (proj == 2) {
      // --- V: transpose 128x128 tile via LDS, store [bh][d][s] coalesced ---
      __shared__ __align__(16) unsigned short VT[128 * 136];
#pragma unroll
      for (int n = 0; n < 4; n++) {
        const int cl = wc * 64 + n * 16 + lrow;  // local col (d-direction)
        const float bval = bias[bn + cl];
#pragma unroll
        for (int m = 0; m < 4; m++)
#pragma unroll
          for (int r = 0; r < 4; r++)
            VT[cl * 136 + wr * 64 + m * 16 + lgrp * 4 + r] = f2bf(acc[m][n][r] + bval);
      }
      __syncthreads();
      const int j = (bn - 1024) >> 7;   // 0..3
      const int b = bm >> 11;
      const int sbase = bm & 2047;
      unsigned short* vout = outb + (size_t)2 * 4194304;
#pragma unroll
      for (int q = 0; q < 8; q++) {
        const int chunk = q * 256 + tid;       // 2048 chunks of 8 elems
        const int cl = chunk >> 4, s8 = chunk & 15;
        const int head = 2 * j + (cl >> 6), d = cl & 63;
        ushort8 val = *(const ushort8*)&VT[cl * 136 + s8 * 8];
        *(ushort8*)(vout + ((size_t)(b * 8 + head) * 64 + d) * 2048 + sbase + s8 * 8) = val;
      }
    } else {
      const float qs = (proj == 0) ? 0.18033688011f : 1.0f;  // log2(e)/8
#pragma unroll
      for (int m = 0; m < 4; m++) {
#pragma unroll
        for (int n = 0; n < 4; n++) {
          const int gcol = bn + wc * 64 + n * 16 + lrow;
          const float bval = bias[gcol];
          const int feat = gcol & 511;
          const int head = feat >> 6, d = feat & 63;
#pragma unroll
          for (int r = 0; r < 4; r++) {
            const int grow = bm + wr * 64 + m * 16 + lgrp * 4 + r;
            const int b = grow >> 11, s = grow & 2047;
            const int bh = b * 8 + head;
            outb[(size_t)proj * 4194304 + ((size_t)bh * 2048 + s) * 64 + d] =
                f2bf((acc[m][n][r] + bval) * qs);
          }
        }
      }
    }
  } else {
#pragma unroll
    for (int m = 0; m < 4; m++) {
#pragma unroll
      for (int n = 0; n < 4; n++) {
        const int gcol = bn + wc * 64 + n * 16 + lrow;
        const float bval = bias[gcol];
#pragma unroll
        for (int r = 0; r < 4; r++) {
          const int grow = bm + wr * 64 + m * 16 + lgrp * 4 + r;
          float v = acc[m][n][r] + bval;
          const size_t o = (size_t)grow * N + gcol;
          if constexpr (EPI == 1) {
            outb[o] = f2bf(v + bf2f(residb[o]));
          } else if constexpr (EPI == 2) {
            outb[o] = f2bf(v > 0.f ? v : 0.f);
          } else {
            outf[o] = v + bf2f(residb[o]);
          }
        }
      }
    }
  }
}

// ---------------------------------------------------------------------------
// GEMM 256x128 tile, 8 waves (4M x 2N, 64x64 per wave), BK=64.
// Fixed to FFN1 shape (ReLU epilogue, N multiple of 128).
// ---------------------------------------------------------------------------
__global__ __launch_bounds__(512) void gemm_ffn1(
    const unsigned short* __restrict__ A, const unsigned short* __restrict__ Bw,
    const float* __restrict__ bias, int M, int N, int K,
    unsigned short* __restrict__ outb) {
  __shared__ __align__(16) unsigned short As[256 * 64];
  __shared__ __align__(16) unsigned short Bs[128 * 64];
  const int tid = threadIdx.x;
  const int lane = tid & 63;
  const int wv = tid >> 6;          // 0..7
  const int wr = wv >> 1, wc = wv & 1;
  const int lrow = lane & 15, lgrp = lane >> 4;
  const int bm = blockIdx.x * 256;
  const int bn = blockIdx.y * 128;

  f32x4 acc[4][4];
#pragma unroll
  for (int m = 0; m < 4; m++)
#pragma unroll
    for (int n = 0; n < 4; n++) acc[m][n] = (f32x4){0.f, 0.f, 0.f, 0.f};

  for (int k0 = 0; k0 < K; k0 += 64) {
    __syncthreads();
    // A tile: 256x64 = 2048 chunks, 4 per thread
#pragma unroll
    for (int i = 0; i < 4; i++) {
      const int sb = wv * 64 + i * 512;   // wave-uniform LDS slot base
      const int slot = sb + lane;
      const int row = slot >> 3;
      const int cc = (slot & 7) ^ (row & 7);
      gload_lds16(A + (size_t)(bm + row) * K + k0 + cc * 8, &As[sb * 8]);
    }
    // B tile: 128x64 = 1024 chunks, 2 per thread
#pragma unroll
    for (int i = 0; i < 2; i++) {
      const int sb = wv * 64 + i * 512;
      const int slot = sb + lane;
      const int row = slot >> 3;
      const int cc = (slot & 7) ^ (row & 7);
      gload_lds16(Bw + (size_t)(bn + row) * K + k0 + cc * 8, &Bs[sb * 8]);
    }
    __syncthreads();

#pragma unroll
    for (int kk = 0; kk < 2; kk++) {
      short8 af[4], bfr[4];
#pragma unroll
      for (int m = 0; m < 4; m++) {
        const int row = wr * 64 + m * 16 + lrow;
        af[m] = *(const short8*)&As[row * 64 + (((lgrp + 4 * kk) ^ (row & 7)) * 8)];
      }
#pragma unroll
      for (int n = 0; n < 4; n++) {
        const int row = wc * 64 + n * 16 + lrow;
        bfr[n] = *(const short8*)&Bs[row * 64 + (((lgrp + 4 * kk) ^ (row & 7)) * 8)];
      }
#pragma unroll
      for (int m = 0; m < 4; m++)
#pragma unroll
        for (int n = 0; n < 4; n++)
          acc[m][n] = __builtin_amdgcn_mfma_f32_16x16x32_bf16(af[m], bfr[n], acc[m][n], 0, 0, 0);
    }
  }

#pragma unroll
  for (int m = 0; m < 4; m++) {
#pragma unroll
    for (int n = 0; n < 4; n++) {
      const int gcol = bn + wc * 64 + n * 16 + lrow;
      const float bval = bias[gcol];
#pragma unroll
      for (int r = 0; r < 4; r++) {
        const int grow = bm + wr * 64 + m * 16 + lgrp * 4 + r;
        const float v = acc[m][n][r] + bval;
        outb[(size_t)grow * N + gcol] = f2bf(v > 0.f ? v : 0.f);
      }
    }
  }
}

// ---------------------------------------------------------------------------
// GEMM 256x64 tile, 8 waves (each wave 32 rows x 64 cols), BK=128.
// 80 KB LDS -> exactly 2 blocks/CU (160 KB pool) = 4 waves/SIMD; per-CU
// barrier instances halved vs the 128x64 4-wave version while each barrier
// covers 2x compute. __launch_bounds__(512,4) caps VGPR at 128 (no spill:
// acc 32 + frags ~24 + addr ~30). EPI 1: bf16 out + bf16 residual.
// ---------------------------------------------------------------------------
template <int EPI>
__global__ __launch_bounds__(512, 4) void gemm_n64(
    const unsigned short* __restrict__ A, const unsigned short* __restrict__ Bw,
    const float* __restrict__ bias, int M, int N, int K,
    unsigned short* __restrict__ outb, float* __restrict__ outf,
    const unsigned short* __restrict__ residb) {
  __shared__ __align__(16) unsigned short As[256 * 128];
  __shared__ __align__(16) unsigned short Bs[64 * 128];
  const int tid = threadIdx.x;
  const int lane = tid & 63;
  const int wv = tid >> 6;          // 0..7
  const int lrow = lane & 15, lgrp = lane >> 4;
  const int bm = blockIdx.x * 256;
  const int bn = blockIdx.y * 64;

  f32x4 acc[2][4];
#pragma unroll
  for (int m = 0; m < 2; m++)
#pragma unroll
    for (int n = 0; n < 4; n++) acc[m][n] = (f32x4){0.f, 0.f, 0.f, 0.f};

  for (int k0 = 0; k0 < K; k0 += 128) {
    __syncthreads();
    // A tile: 256x128 = 4096 chunks, 8 per thread (512 thr)
#pragma unroll
    for (int i = 0; i < 8; i++) {
      const int sb = wv * 64 + i * 512;
      const int slot = sb + lane;
      const int row = slot >> 4;
      const int cc = (slot & 15) ^ (row & 15);
      gload_lds16(A + (size_t)(bm + row) * K + k0 + cc * 8, &As[sb * 8]);
    }
    // B tile: 64x128 = 1024 chunks, 2 per thread
#pragma unroll
    for (int i = 0; i < 2; i++) {
      const int sb = wv * 64 + i * 512;
      const int slot = sb + lane;
      const int row = slot >> 4;
      const int cc = (slot & 15) ^ (row & 15);
      gload_lds16(Bw + (size_t)(bn + row) * K + k0 + cc * 8, &Bs[sb * 8]);
    }
    __syncthreads();

#pragma unroll
    for (int kk = 0; kk < 4; kk++) {
      short8 af[2], bfr[4];
#pragma unroll
      for (int m = 0; m < 2; m++) {
        const int row = wv * 32 + m * 16 + lrow;
        af[m] = *(const short8*)&As[row * 128 + (((lgrp + 4 * kk) ^ (row & 15)) * 8)];
      }
#pragma unroll
      for (int n = 0; n < 4; n++) {
        const int row = n * 16 + lrow;
        bfr[n] = *(const short8*)&Bs[row * 128 + (((lgrp + 4 * kk) ^ (row & 15)) * 8)];
      }
#pragma unroll
      for (int m = 0; m < 2; m++)
#pragma unroll
        for (int n = 0; n < 4; n++)
          acc[m][n] = __builtin_amdgcn_mfma_f32_16x16x32_bf16(af[m], bfr[n], acc[m][n], 0, 0, 0);
    }
  }

#pragma unroll
  for (int m = 0; m < 2; m++) {
#pragma unroll
    for (int n = 0; n < 4; n++) {
      const int gcol = bn + n * 16 + lrow;
      const float bval = bias[gcol];
#pragma unroll
      for (int r = 0; r < 4; r++) {
        const int grow = bm + wv * 32 + m * 16 + lgrp * 4 + r;
        float v = acc[m][n][r] + bval;
        const size_t o = (size_t)grow * N + gcol;
        outb[o] = f2bf(v + bf2f(residb[o]));
      }
    }
  }
}

// ---------------------------------------------------------------------------
// Flash attention (r19): 8 waves x 32 q, KVBLK=256 (128 KB LDS, 1 block/CU,
// 2 waves/SIMD), 8 iterations with two 128-k compute phases per barrier.
// Swapped QK^T 32x32x16, in-register P via permlane32_swap, ILP-widened
// (4 QK chains, 6 PV chains incl. ones-MFMA denominator).
// ---------------------------------------------------------------------------
__global__ __launch_bounds__(512, 1) void attn_k(
    const unsigned short* __restrict__ Qg, const unsigned short* __restrict__ Kg,
    const unsigned short* __restrict__ Vg, unsigned short* __restrict__ Og) {
  __shared__ __align__(16) unsigned short Kl[2][256 * 64];
  __shared__ __align__(16) unsigned short Vl[2][64 * 256];
  const int tid = threadIdx.x, lane = tid & 63, wq = tid >> 6;  // wq 0..7
  const int ql = lane & 31;   // q-column (QK) / d-column (PV)
  const int hi = lane >> 5;
  const int bid = blockIdx.x;
  // XCD-chunked: 256 blocks, 32 per XCD -> 4 heads per XCD
  const int lin = (bid & 7) * 32 + (bid >> 3);
  const int bh = lin >> 3;          // head
  const int q0 = (lin & 7) * 256;   // 256-row q-slab per block
  const int qw = q0 + wq * 32;      // wave's q base
  const size_t hbase = (size_t)bh * (2048 * 64);

  // staging geometry: 4 K-chunk + 4 V-chunk slots per thread (512 thr)
  int kR[4], kC[4], vR[4], vC[4];
#pragma unroll
  for (int i = 0; i < 4; i++) {
    const int slot = i * 512 + tid;
    kR[i] = slot >> 3;                       // 0..255
    kC[i] = (slot & 7) ^ (kR[i] & 7);
    vR[i] = slot >> 5;                       // 0..63
    vC[i] = (slot & 31) ^ (vR[i] & 31);
  }

  // Q regs: qreg[i] = Q[qw+ql][16i + hi*8 .. +7]  (B-frag for QK mfma #i)
  short8 qreg[4];
  {
    const unsigned short* qp = Qg + hbase + (size_t)(qw + ql) * 64 + hi * 8;
#pragma unroll
    for (int i = 0; i < 4; i++) qreg[i] = *(const short8*)(qp + 16 * i);
  }

  // all-ones bf16 B-frag for the denominator MFMA
  const unsigned one2 = 0x3F803F80u;
  const short8 ones = pack4(one2, one2, one2, one2);

  const f32x16 zz = {0.f, 0.f, 0.f, 0.f, 0.f, 0.f, 0.f, 0.f,
                     0.f, 0.f, 0.f, 0.f, 0.f, 0.f, 0.f, 0.f};
  f32x16 oA0 = zz, oA1 = zz, lA = zz;
  f32x16 oB0 = zz, oB1 = zz, lB = zz;

  // prologue: stage k-slab 0 (k 0..255) into buffer 0
#pragma unroll
  for (int i = 0; i < 4; i++) {
    const int db = (i * 512 + wq * 64) * 8;   // wave-uniform dest elem base
    gload_lds16(Kg + hbase + (size_t)kR[i] * 64 + kC[i] * 8, &Kl[0][db]);
    gload_lds16(Vg + hbase + (size_t)vR[i] * 2048 + vC[i] * 8, &Vl[0][db]);
  }
  __syncthreads();

  for (int it = 0; it < 8; ++it) {
    const int cur = it & 1;
    if (it < 7) {
      const int kt = (it + 1) * 256;
      const int nxt = cur ^ 1;
#pragma unroll
      for (int i = 0; i < 4; i++) {
        const int db = (i * 512 + wq * 64) * 8;
        gload_lds16(Kg + hbase + (size_t)(kt + kR[i]) * 64 + kC[i] * 8, &Kl[nxt][db]);
        gload_lds16(Vg + hbase + (size_t)vR[i] * 2048 + kt + vC[i] * 8, &Vl[nxt][db]);
      }
    }

#pragma unroll
    for (int hf = 0; hf < 2; hf++) {   // two 128-k compute phases per barrier
      const int koff = hf * 128;

      // QK^T over this 128-k half: 4 independent chains sc[t]
      f32x16 sc[4] = {zz, zz, zz, zz};
      __builtin_amdgcn_s_setprio(1);
#pragma unroll
      for (int i = 0; i < 4; i++) {
        const int c8 = 2 * i + hi;
#pragma unroll
        for (int t = 0; t < 4; t++) {
          const int r = koff + 32 * t + ql;
          short8 ka = *(const short8*)&Kl[cur][(r * 8 + (c8 ^ (r & 7))) * 8];
          sc[t] = __builtin_amdgcn_mfma_f32_32x32x16_bf16(ka, qreg[i], sc[t], 0, 0, 0);
        }
      }
      __builtin_amdgcn_s_setprio(0);

      // softmax (no-max: Q pre-scaled by log2e/8) + in-register P via permlane
      short8 pa[8];
#pragma unroll
      for (int t = 0; t < 4; t++) {
        float p[16];
#pragma unroll
        for (int r = 0; r < 16; r++) p[r] = __builtin_amdgcn_exp2f(sc[t][r]);
        unsigned w0a = cvtpk(p[0], p[1]),   w0b = cvtpk(p[2], p[3]);
        unsigned w1a = cvtpk(p[4], p[5]),   w1b = cvtpk(p[6], p[7]);
        unsigned w2a = cvtpk(p[8], p[9]),   w2b = cvtpk(p[10], p[11]);
        unsigned w3a = cvtpk(p[12], p[13]), w3b = cvtpk(p[14], p[15]);
        pl32(w0a, w1a);
        pl32(w0b, w1b);
        pa[2 * t] = pack4(w0a, w0b, w1a, w1b);
        pl32(w2a, w3a);
        pl32(w2b, w3b);
        pa[2 * t + 1] = pack4(w2a, w2b, w3a, w3b);
      }

      // PV over 8 k-slices of this half; even ks -> A-chains, odd -> B-chains
      __builtin_amdgcn_s_setprio(1);
#pragma unroll
      for (int ks = 0; ks < 8; ks += 2) {
        const int c8e = hf * 16 + 2 * ks + hi;
        const int c8o = hf * 16 + 2 * (ks + 1) + hi;
        const int r0 = ql, r1 = ql + 32;
        short8 ve0 = *(const short8*)&Vl[cur][(r0 * 32 + (c8e ^ (r0 & 31))) * 8];
        short8 ve1 = *(const short8*)&Vl[cur][(r1 * 32 + (c8e ^ (r1 & 31))) * 8];
        short8 vo0 = *(const short8*)&Vl[cur][(r0 * 32 + (c8o ^ (r0 & 31))) * 8];
        short8 vo1 = *(const short8*)&Vl[cur][(r1 * 32 + (c8o ^ (r1 & 31))) * 8];
        oA0 = __builtin_amdgcn_mfma_f32_32x32x16_bf16(pa[ks], ve0, oA0, 0, 0, 0);
        oA1 = __builtin_amdgcn_mfma_f32_32x32x16_bf16(pa[ks], ve1, oA1, 0, 0, 0);
        lA = __builtin_amdgcn_mfma_f32_32x32x16_bf16(pa[ks], ones, lA, 0, 0, 0);
        oB0 = __builtin_amdgcn_mfma_f32_32x32x16_bf16(pa[ks + 1], vo0, oB0, 0, 0, 0);
        oB1 = __builtin_amdgcn_mfma_f32_32x32x16_bf16(pa[ks + 1], vo1, oB1, 0, 0, 0);
        lB = __builtin_amdgcn_mfma_f32_32x32x16_bf16(pa[ks + 1], ones, lB, 0, 0, 0);
      }
      __builtin_amdgcn_s_setprio(0);
    }

    __syncthreads();  // next-slab loads landed + all waves done with cur
  }

  const int b = bh >> 3, h = bh & 7;
#pragma unroll
  for (int r = 0; r < 16; r++) {
    const int qrow = (r & 3) + 8 * (r >> 2) + 4 * hi;  // crow(r,hi) = q-local
    const float invr = 1.0f / (lA[r] + lB[r]);
    const size_t base = ((size_t)(b * 2048 + qw + qrow)) * 512 + h * 64 + ql;
    Og[base] = f2bf((oA0[r] + oB0[r]) * invr);
    Og[base + 32] = f2bf((oA1[r] + oB1[r]) * invr);
  }
}

// ---------------------------------------------------------------------------
// LayerNorm over last dim (512), one wave per token.
// ln_bf_k:   bf16 in -> bf16 out
// ln_bf2f_k: bf16 in -> fp32 out
// ---------------------------------------------------------------------------
__global__ __launch_bounds__(64) void ln_bf_k(const unsigned short* __restrict__ in,
                                              const float* __restrict__ g,
                                              const float* __restrict__ bb,
                                              unsigned short* __restrict__ out) {
  const int row = blockIdx.x, lane = threadIdx.x;
  ushort8 v = *(const ushort8*)(in + (size_t)row * 512 + lane * 8);
  float f[8];
#pragma unroll
  for (int j = 0; j < 8; j++) f[j] = bf2f(v[j]);
  float s = 0.f;
#pragma unroll
  for (int j = 0; j < 8; j++) s += f[j];
#pragma unroll
  for (int off = 32; off >= 1; off >>= 1) s += __shfl_xor(s, off);
  const float mu = s * (1.f / 512.f);
  float q = 0.f;
#pragma unroll
  for (int j = 0; j < 8; j++) { const float d = f[j] - mu; q += d * d; }
#pragma unroll
  for (int off = 32; off >= 1; off >>= 1) q += __shfl_xor(q, off);
  const float rstd = rsqrtf(q * (1.f / 512.f) + 1e-5f);
  const float4* gp = (const float4*)g;
  const float4* bp = (const float4*)bb;
  float4 g0 = gp[lane * 2], g1 = gp[lane * 2 + 1];
  float4 c0 = bp[lane * 2], c1 = bp[lane * 2 + 1];
  const float gg[8] = {g0.x, g0.y, g0.z, g0.w, g1.x, g1.y, g1.z, g1.w};
  const float cc[8] = {c0.x, c0.y, c0.z, c0.w, c1.x, c1.y, c1.z, c1.w};
  ushort8 ov;
#pragma unroll
  for (int j = 0; j < 8; j++) ov[j] = f2bf((f[j] - mu) * rstd * gg[j] + cc[j]);
  *(ushort8*)(out + (size_t)row * 512 + lane * 8) = ov;
}

__global__ __launch_bounds__(64) void ln_bf2f_k(const unsigned short* __restrict__ in,
                                                const float* __restrict__ g,
                                                const float* __restrict__ bb,
                                                float* __restrict__ outf) {
  const int row = blockIdx.x, lane = threadIdx.x;
  ushort8 v = *(const ushort8*)(in + (size_t)row * 512 + lane * 8);
  float f[8];
#pragma unroll
  for (int j = 0; j < 8; j++) f[j] = bf2f(v[j]);
  float s = 0.f;
#pragma unroll
  for (int j = 0; j < 8; j++) s += f[j];
#pragma unroll
  for (int off = 32; off >= 1; off >>= 1) s += __shfl_xor(s, off);
  const float mu = s * (1.f / 512.f);
  float q = 0.f;
#pragma unroll
  for (int j = 0; j < 8; j++) { const float d = f[j] - mu; q += d * d; }
#pragma unroll
  for (int off = 32; off >= 1; off >>= 1) q += __shfl_xor(q, off);
  const float rstd = rsqrtf(q * (1.f / 512.f) + 1e-5f);
  const float4* gp = (const float4*)g;
  const float4* bp = (const float4*)bb;
  float4 g0 = gp[lane * 2], g1 = gp[lane * 2 + 1];
  float4 c0 = bp[lane * 2], c1 = bp[lane * 2 + 1];
  const float gg[8] = {g0.x, g0.y, g0.z, g0.w, g1.x, g1.y, g1.z, g1.w};
  const float cc[8] = {c0.x, c0.y, c0.z, c0.w, c1.x, c1.y, c1.z, c1.w};
  float4 o0, o1;
  float* o0p = &o0.x;
  float* o1p = &o1.x;
#pragma unroll
  for (int j = 0; j < 4; j++) o0p[j] = (f[j] - mu) * rstd * gg[j] + cc[j];
#pragma unroll
  for (int j = 0; j < 4; j++) o1p[j] = (f[j + 4] - mu) * rstd * gg[j + 4] + cc[j + 4];
  float4* of = (float4*)(outf + (size_t)row * 512 + lane * 8);
  of[0] = o0;
  of[1] = o1;
}

// ---------------------------------------------------------------------------
extern "C" void kernel_launch(void* const* d_in, const int* in_sizes, int n_in,
                              void* d_out, int out_size, void* d_ws, size_t ws_size,
                              hipStream_t stream) {
  const float* x = (const float*)d_in[0];
  const float* wq = (const float*)d_in[1];
  const float* bq = (const float*)d_in[2];
  const float* wk = (const float*)d_in[3];
  const float* bk = (const float*)d_in[4];
  const float* wv = (const float*)d_in[5];
  const float* bv = (const float*)d_in[6];
  const float* wo = (const float*)d_in[7];
  const float* bo = (const float*)d_in[8];
  const float* ln_g = (const float*)d_in[9];
  const float* ln_b = (const float*)d_in[10];
  const float* w1 = (const float*)d_in[11];
  const float* b1 = (const float*)d_in[12];
  const float* w2 = (const float*)d_in[13];
  const float* b2 = (const float*)d_in[14];

  // workspace carve-up (ushort elems)
  unsigned short* ws_u = (unsigned short*)d_ws;
  unsigned short* wqkv = ws_u;                   // 786432
  unsigned short* wob = wqkv + 786432;           // 262144
  unsigned short* w1b = wob + 262144;            // 1048576
  unsigned short* w2b = w1b + 1048576;           // 1048576
  unsigned short* xb = w2b + 1048576;            // 4194304  [8192][512]
  unsigned short* qb = xb + 4194304;             // [32][2048][64]
  unsigned short* kb = qb + 4194304;             // [32][2048][64]
  unsigned short* vtb = kb + 4194304;            // V^T [32][64][2048]
  unsigned short* ob = vtb + 4194304;            // attn out [8192][512]
  unsigned short* s1b = ob + 4194304;            // h_pre bf16 / y2 bf16 [8192][512]
  unsigned short* hb = s1b + 4194304;            // h bf16 [8192][512]
  unsigned short* f1b = qb;                      // reuse qb..ob: [8192][2048]
  float* bqkv = (float*)(hb + 4194304);          // 1536

  // one fused convert+bias launch for all weights + x
  cvt_all_k<<<7169, 256, 0, stream>>>(
      (const float4*)wq, (const float4*)wk, (const float4*)wv, (const float4*)wo,
      (const float4*)w1, (const float4*)w2, (const float4*)x,
      (ushort4v*)wqkv, (ushort4v*)wob, (ushort4v*)w1b, (ushort4v*)w2b,
      (ushort4v*)xb, bq, bk, bv, bqkv);

  // QKV projection: M=8192, N=1536, K=512 -> scatter into qb/kb/vtb
  gemm_bt<0><<<dim3(64, 12), 256, 0, stream>>>(xb, wqkv, bqkv, 8192, 1536, 512,
                                               qb, nullptr, nullptr);
  // attention (256 blocks x 512 threads, XCD-chunked internally)
  attn_k<<<256, 512, 0, stream>>>(qb, kb, vtb, ob);
  // O projection + residual(xb): -> s1b bf16  (256x64 tiles, 8 waves, BK=128)
  gemm_n64<1><<<dim3(32, 8), 512, 0, stream>>>(ob, wob, bo, 8192, 512, 512,
                                               s1b, nullptr, xb);
  // LN1 (bf16 -> bf16)
  ln_bf_k<<<8192, 64, 0, stream>>>(s1b, ln_g, ln_b, hb);
  // FFN1 + ReLU: M=8192, N=2048, K=512 -> f1b bf16 (256x128 tiles, 8 waves)
  gemm_ffn1<<<dim3(32, 16), 512, 0, stream>>>(hb, w1b, b1, 8192, 2048, 512, f1b);
  // FFN2 + residual(hb): M=8192, N=512, K=2048 -> s1b bf16 (256x64, BK=128)
  gemm_n64<1><<<dim3(32, 8), 512, 0, stream>>>(f1b, w2b, b2, 8192, 512, 2048,
                                               s1b, nullptr, hb);
  // LN2: bf16 in -> fp32 d_out
  ln_bf2f_k<<<8192, 64, 0, stream>>>(s1b, ln_g, ln_b, (float*)d_out);
}

// Round 21
// 149.716 us; speedup vs baseline: 1.0505x; 1.0505x over previous
//
#include <hip/hip_runtime.h>

typedef __attribute__((ext_vector_type(8))) short short8;
typedef __attribute__((ext_vector_type(8))) unsigned short ushort8;
typedef __attribute__((ext_vector_type(4))) unsigned short ushort4v;
typedef __attribute__((ext_vector_type(4))) float f32x4;
typedef __attribute__((ext_vector_type(16))) float f32x16;

#define DEV static __device__ __forceinline__

DEV unsigned short f2bf(float f) {
  unsigned u = __builtin_bit_cast(unsigned, f);
  u += 0x7fffu + ((u >> 16) & 1u);
  return (unsigned short)(u >> 16);
}

DEV float bf2f(unsigned short u) {
  return __builtin_bit_cast(float, (unsigned)u << 16);
}

DEV void gload_lds16(const void* g, void* l) {
  __builtin_amdgcn_global_load_lds((__attribute__((address_space(1))) void*)g,
                                   (__attribute__((address_space(3))) void*)l,
                                   16, 0, 0);
}

DEV unsigned cvtpk(float lo, float hi) {
  unsigned u;
  asm("v_cvt_pk_bf16_f32 %0, %1, %2" : "=v"(u) : "v"(lo), "v"(hi));
  return u;
}

// v_permlane32_swap_b32 a, b:  lane<32: a'=own a, b'=partner(l+32)'s a;
// lane>=32: a'=partner's b, b'=own b.
DEV void pl32(unsigned& a, unsigned& b) {
  asm("v_permlane32_swap_b32 %0, %1" : "+v"(a), "+v"(b));
}

DEV short8 pack4(unsigned a, unsigned b, unsigned c, unsigned d) {
  int4 t = make_int4((int)a, (int)b, (int)c, (int)d);
  return __builtin_bit_cast(short8, t);
}

// ---------------------------------------------------------------------------
// fused fp32 -> bf16 convert for all 7 regions + bias pack, ONE launch.
// ---------------------------------------------------------------------------
__global__ __launch_bounds__(256) void cvt_all_k(
    const float4* __restrict__ wq, const float4* __restrict__ wk,
    const float4* __restrict__ wv, const float4* __restrict__ wo,
    const float4* __restrict__ w1, const float4* __restrict__ w2,
    const float4* __restrict__ x, ushort4v* __restrict__ wqkv,
    ushort4v* __restrict__ wob, ushort4v* __restrict__ w1b,
    ushort4v* __restrict__ w2b, ushort4v* __restrict__ xb,
    const float* __restrict__ bq, const float* __restrict__ bk,
    const float* __restrict__ bv, float* __restrict__ bo) {
  const int i = threadIdx.x;
  const int b = blockIdx.x;
  if (b >= 7168) {  // bias pack
#pragma unroll
    for (int j = 0; j < 2; j++) {
      const int idx = j * 256 + i;
      bo[idx] = bq[idx];
      bo[512 + idx] = bk[idx];
      bo[1024 + idx] = bv[idx];
    }
    return;
  }
  const float4* s;
  ushort4v* d;
  size_t u;
  if (b < 256)       { s = wq; d = wqkv;          u = (size_t)b * 256 + i; }
  else if (b < 512)  { s = wk; d = wqkv + 65536;  u = (size_t)(b - 256) * 256 + i; }
  else if (b < 768)  { s = wv; d = wqkv + 131072; u = (size_t)(b - 512) * 256 + i; }
  else if (b < 1024) { s = wo; d = wob;           u = (size_t)(b - 768) * 256 + i; }
  else if (b < 2048) { s = w1; d = w1b;           u = (size_t)(b - 1024) * 256 + i; }
  else if (b < 3072) { s = w2; d = w2b;           u = (size_t)(b - 2048) * 256 + i; }
  else               { s = x;  d = xb;            u = (size_t)(b - 3072) * 256 + i; }
  float4 v = s[u];
  ushort4v o = { f2bf(v.x), f2bf(v.y), f2bf(v.z), f2bf(v.w) };
  d[u] = o;
}

// ---------------------------------------------------------------------------
// GEMM 128x128, BK=64, 4 waves. Source-pre-swizzled staging.
// EPI 0: QKV scatter. Q (scaled by log2e/8) -> [bh][s][d], K -> [bh][s][d],
//        V -> TRANSPOSED [bh][d][s] via LDS-transpose (coalesced stores).
// ---------------------------------------------------------------------------
template <int EPI>
__global__ __launch_bounds__(256) void gemm_bt(
    const unsigned short* __restrict__ A, const unsigned short* __restrict__ Bw,
    const float* __restrict__ bias, int M, int N, int K,
    unsigned short* __restrict__ outb, float* __restrict__ outf,
    const unsigned short* __restrict__ residb) {
  __shared__ __align__(16) unsigned short As[128 * 64];
  __shared__ __align__(16) unsigned short Bs[128 * 64];
  const int tid = threadIdx.x;
  const int lane = tid & 63;
  const int wv = tid >> 6;
  const int wr = wv >> 1, wc = wv & 1;
  const int lrow = lane & 15, lgrp = lane >> 4;
  const int bm = blockIdx.x * 128;
  const int bn = blockIdx.y * 128;

  f32x4 acc[4][4];
#pragma unroll
  for (int m = 0; m < 4; m++)
#pragma unroll
    for (int n = 0; n < 4; n++) acc[m][n] = (f32x4){0.f, 0.f, 0.f, 0.f};

  for (int k0 = 0; k0 < K; k0 += 64) {
    __syncthreads();
#pragma unroll
    for (int i = 0; i < 4; i++) {
      const int sb = wv * 64 + i * 256;   // wave-uniform LDS slot base
      const int slot = sb + lane;
      const int row = slot >> 3;
      const int cc = (slot & 7) ^ (row & 7);   // pre-swizzled source chunk
      gload_lds16(A + (size_t)(bm + row) * K + k0 + cc * 8, &As[sb * 8]);
      gload_lds16(Bw + (size_t)(bn + row) * K + k0 + cc * 8, &Bs[sb * 8]);
    }
    __syncthreads();

#pragma unroll
    for (int kk = 0; kk < 2; kk++) {
      short8 af[4], bfr[4];
#pragma unroll
      for (int m = 0; m < 4; m++) {
        const int row = wr * 64 + m * 16 + lrow;
        af[m] = *(const short8*)&As[row * 64 + (((lgrp + 4 * kk) ^ (row & 7)) * 8)];
      }
#pragma unroll
      for (int n = 0; n < 4; n++) {
        const int row = wc * 64 + n * 16 + lrow;
        bfr[n] = *(const short8*)&Bs[row * 64 + (((lgrp + 4 * kk) ^ (row & 7)) * 8)];
      }
#pragma unroll
      for (int m = 0; m < 4; m++)
#pragma unroll
        for (int n = 0; n < 4; n++)
          acc[m][n] = __builtin_amdgcn_mfma_f32_16x16x32_bf16(af[m], bfr[n], acc[m][n], 0, 0, 0);
    }
  }

  if constexpr (EPI == 0) {
    const int proj = bn >> 9;  // block-uniform: 0=Q, 1=K, 2=V
    if (proj == 2) {
      // --- V: transpose 128x128 tile via LDS, store [bh][d][s] coalesced ---
      __shared__ __align__(16) unsigned short VT[128 * 136];
#pragma unroll
      for (int n = 0; n < 4; n++) {
        const int cl = wc * 64 + n * 16 + lrow;  // local col (d-direction)
        const float bval = bias[bn + cl];
#pragma unroll
        for (int m = 0; m < 4; m++)
#pragma unroll
          for (int r = 0; r < 4; r++)
            VT[cl * 136 + wr * 64 + m * 16 + lgrp * 4 + r] = f2bf(acc[m][n][r] + bval);
      }
      __syncthreads();
      const int j = (bn - 1024) >> 7;   // 0..3
      const int b = bm >> 11;
      const int sbase = bm & 2047;
      unsigned short* vout = outb + (size_t)2 * 4194304;
#pragma unroll
      for (int q = 0; q < 8; q++) {
        const int chunk = q * 256 + tid;       // 2048 chunks of 8 elems
        const int cl = chunk >> 4, s8 = chunk & 15;
        const int head = 2 * j + (cl >> 6), d = cl & 63;
        ushort8 val = *(const ushort8*)&VT[cl * 136 + s8 * 8];
        *(ushort8*)(vout + ((size_t)(b * 8 + head) * 64 + d) * 2048 + sbase + s8 * 8) = val;
      }
    } else {
      const float qs = (proj == 0) ? 0.18033688011f : 1.0f;  // log2(e)/8
#pragma unroll
      for (int m = 0; m < 4; m++) {
#pragma unroll
        for (int n = 0; n < 4; n++) {
          const int gcol = bn + wc * 64 + n * 16 + lrow;
          const float bval = bias[gcol];
          const int feat = gcol & 511;
          const int head = feat >> 6, d = feat & 63;
#pragma unroll
          for (int r = 0; r < 4; r++) {
            const int grow = bm + wr * 64 + m * 16 + lgrp * 4 + r;
            const int b = grow >> 11, s = grow & 2047;
            const int bh = b * 8 + head;
            outb[(size_t)proj * 4194304 + ((size_t)bh * 2048 + s) * 64 + d] =
                f2bf((acc[m][n][r] + bval) * qs);
          }
        }
      }
    }
  } else {
#pragma unroll
    for (int m = 0; m < 4; m++) {
#pragma unroll
      for (int n = 0; n < 4; n++) {
        const int gcol = bn + wc * 64 + n * 16 + lrow;
        const float bval = bias[gcol];
#pragma unroll
        for (int r = 0; r < 4; r++) {
          const int grow = bm + wr * 64 + m * 16 + lgrp * 4 + r;
          float v = acc[m][n][r] + bval;
          const size_t o = (size_t)grow * N + gcol;
          if constexpr (EPI == 1) {
            outb[o] = f2bf(v + bf2f(residb[o]));
          } else if constexpr (EPI == 2) {
            outb[o] = f2bf(v > 0.f ? v : 0.f);
          } else {
            outf[o] = v + bf2f(residb[o]);
          }
        }
      }
    }
  }
}

// ---------------------------------------------------------------------------
// GEMM 256x128 tile, 8 waves (4M x 2N, 64x64 per wave), BK=64.
// Fixed to FFN1 shape (ReLU epilogue, N multiple of 128).
// ---------------------------------------------------------------------------
__global__ __launch_bounds__(512) void gemm_ffn1(
    const unsigned short* __restrict__ A, const unsigned short* __restrict__ Bw,
    const float* __restrict__ bias, int M, int N, int K,
    unsigned short* __restrict__ outb) {
  __shared__ __align__(16) unsigned short As[256 * 64];
  __shared__ __align__(16) unsigned short Bs[128 * 64];
  const int tid = threadIdx.x;
  const int lane = tid & 63;
  const int wv = tid >> 6;          // 0..7
  const int wr = wv >> 1, wc = wv & 1;
  const int lrow = lane & 15, lgrp = lane >> 4;
  const int bm = blockIdx.x * 256;
  const int bn = blockIdx.y * 128;

  f32x4 acc[4][4];
#pragma unroll
  for (int m = 0; m < 4; m++)
#pragma unroll
    for (int n = 0; n < 4; n++) acc[m][n] = (f32x4){0.f, 0.f, 0.f, 0.f};

  for (int k0 = 0; k0 < K; k0 += 64) {
    __syncthreads();
    // A tile: 256x64 = 2048 chunks, 4 per thread
#pragma unroll
    for (int i = 0; i < 4; i++) {
      const int sb = wv * 64 + i * 512;   // wave-uniform LDS slot base
      const int slot = sb + lane;
      const int row = slot >> 3;
      const int cc = (slot & 7) ^ (row & 7);
      gload_lds16(A + (size_t)(bm + row) * K + k0 + cc * 8, &As[sb * 8]);
    }
    // B tile: 128x64 = 1024 chunks, 2 per thread
#pragma unroll
    for (int i = 0; i < 2; i++) {
      const int sb = wv * 64 + i * 512;
      const int slot = sb + lane;
      const int row = slot >> 3;
      const int cc = (slot & 7) ^ (row & 7);
      gload_lds16(Bw + (size_t)(bn + row) * K + k0 + cc * 8, &Bs[sb * 8]);
    }
    __syncthreads();

#pragma unroll
    for (int kk = 0; kk < 2; kk++) {
      short8 af[4], bfr[4];
#pragma unroll
      for (int m = 0; m < 4; m++) {
        const int row = wr * 64 + m * 16 + lrow;
        af[m] = *(const short8*)&As[row * 64 + (((lgrp + 4 * kk) ^ (row & 7)) * 8)];
      }
#pragma unroll
      for (int n = 0; n < 4; n++) {
        const int row = wc * 64 + n * 16 + lrow;
        bfr[n] = *(const short8*)&Bs[row * 64 + (((lgrp + 4 * kk) ^ (row & 7)) * 8)];
      }
#pragma unroll
      for (int m = 0; m < 4; m++)
#pragma unroll
        for (int n = 0; n < 4; n++)
          acc[m][n] = __builtin_amdgcn_mfma_f32_16x16x32_bf16(af[m], bfr[n], acc[m][n], 0, 0, 0);
    }
  }

#pragma unroll
  for (int m = 0; m < 4; m++) {
#pragma unroll
    for (int n = 0; n < 4; n++) {
      const int gcol = bn + wc * 64 + n * 16 + lrow;
      const float bval = bias[gcol];
#pragma unroll
      for (int r = 0; r < 4; r++) {
        const int grow = bm + wr * 64 + m * 16 + lgrp * 4 + r;
        const float v = acc[m][n][r] + bval;
        outb[(size_t)grow * N + gcol] = f2bf(v > 0.f ? v : 0.f);
      }
    }
  }
}

// ---------------------------------------------------------------------------
// GEMM 128x64 tile, BK=128, 4 waves (each wave 32 rows x 64 cols).
// 48 KB LDS -> 512 blocks (2/CU) for N=512 GEMMs. EPI 1: bf16 + residual.
// ---------------------------------------------------------------------------
template <int EPI>
__global__ __launch_bounds__(256) void gemm_n64(
    const unsigned short* __restrict__ A, const unsigned short* __restrict__ Bw,
    const float* __restrict__ bias, int M, int N, int K,
    unsigned short* __restrict__ outb, float* __restrict__ outf,
    const unsigned short* __restrict__ residb) {
  __shared__ __align__(16) unsigned short As[128 * 128];
  __shared__ __align__(16) unsigned short Bs[64 * 128];
  const int tid = threadIdx.x;
  const int lane = tid & 63;
  const int wv = tid >> 6;
  const int lrow = lane & 15, lgrp = lane >> 4;
  const int bm = blockIdx.x * 128;
  const int bn = blockIdx.y * 64;

  f32x4 acc[2][4];
#pragma unroll
  for (int m = 0; m < 2; m++)
#pragma unroll
    for (int n = 0; n < 4; n++) acc[m][n] = (f32x4){0.f, 0.f, 0.f, 0.f};

  for (int k0 = 0; k0 < K; k0 += 128) {
    __syncthreads();
#pragma unroll
    for (int i = 0; i < 8; i++) {
      const int sb = wv * 64 + i * 256;
      const int slot = sb + lane;
      const int row = slot >> 4;
      const int cc = (slot & 15) ^ (row & 15);
      gload_lds16(A + (size_t)(bm + row) * K + k0 + cc * 8, &As[sb * 8]);
    }
#pragma unroll
    for (int i = 0; i < 4; i++) {
      const int sb = wv * 64 + i * 256;
      const int slot = sb + lane;
      const int row = slot >> 4;
      const int cc = (slot & 15) ^ (row & 15);
      gload_lds16(Bw + (size_t)(bn + row) * K + k0 + cc * 8, &Bs[sb * 8]);
    }
    __syncthreads();

#pragma unroll
    for (int kk = 0; kk < 4; kk++) {
      short8 af[2], bfr[4];
#pragma unroll
      for (int m = 0; m < 2; m++) {
        const int row = wv * 32 + m * 16 + lrow;
        af[m] = *(const short8*)&As[row * 128 + (((lgrp + 4 * kk) ^ (row & 15)) * 8)];
      }
#pragma unroll
      for (int n = 0; n < 4; n++) {
        const int row = n * 16 + lrow;
        bfr[n] = *(const short8*)&Bs[row * 128 + (((lgrp + 4 * kk) ^ (row & 15)) * 8)];
      }
#pragma unroll
      for (int m = 0; m < 2; m++)
#pragma unroll
        for (int n = 0; n < 4; n++)
          acc[m][n] = __builtin_amdgcn_mfma_f32_16x16x32_bf16(af[m], bfr[n], acc[m][n], 0, 0, 0);
    }
  }

#pragma unroll
  for (int m = 0; m < 2; m++) {
#pragma unroll
    for (int n = 0; n < 4; n++) {
      const int gcol = bn + n * 16 + lrow;
      const float bval = bias[gcol];
#pragma unroll
      for (int r = 0; r < 4; r++) {
        const int grow = bm + wv * 32 + m * 16 + lgrp * 4 + r;
        float v = acc[m][n][r] + bval;
        const size_t o = (size_t)grow * N + gcol;
        outb[o] = f2bf(v + bf2f(residb[o]));
      }
    }
  }
}

// ---------------------------------------------------------------------------
// Flash attention (r19): 8 waves x 32 q, KVBLK=256 (128 KB LDS, 1 block/CU,
// 2 waves/SIMD), 8 iterations with two 128-k compute phases per barrier.
// Swapped QK^T 32x32x16, in-register P via permlane32_swap, ILP-widened
// (4 QK chains, 6 PV chains incl. ones-MFMA denominator).
// ---------------------------------------------------------------------------
__global__ __launch_bounds__(512, 1) void attn_k(
    const unsigned short* __restrict__ Qg, const unsigned short* __restrict__ Kg,
    const unsigned short* __restrict__ Vg, unsigned short* __restrict__ Og) {
  __shared__ __align__(16) unsigned short Kl[2][256 * 64];
  __shared__ __align__(16) unsigned short Vl[2][64 * 256];
  const int tid = threadIdx.x, lane = tid & 63, wq = tid >> 6;  // wq 0..7
  const int ql = lane & 31;   // q-column (QK) / d-column (PV)
  const int hi = lane >> 5;
  const int bid = blockIdx.x;
  // XCD-chunked: 256 blocks, 32 per XCD -> 4 heads per XCD
  const int lin = (bid & 7) * 32 + (bid >> 3);
  const int bh = lin >> 3;          // head
  const int q0 = (lin & 7) * 256;   // 256-row q-slab per block
  const int qw = q0 + wq * 32;      // wave's q base
  const size_t hbase = (size_t)bh * (2048 * 64);

  // staging geometry: 4 K-chunk + 4 V-chunk slots per thread (512 thr)
  int kR[4], kC[4], vR[4], vC[4];
#pragma unroll
  for (int i = 0; i < 4; i++) {
    const int slot = i * 512 + tid;
    kR[i] = slot >> 3;                       // 0..255
    kC[i] = (slot & 7) ^ (kR[i] & 7);
    vR[i] = slot >> 5;                       // 0..63
    vC[i] = (slot & 31) ^ (vR[i] & 31);
  }

  // Q regs: qreg[i] = Q[qw+ql][16i + hi*8 .. +7]  (B-frag for QK mfma #i)
  short8 qreg[4];
  {
    const unsigned short* qp = Qg + hbase + (size_t)(qw + ql) * 64 + hi * 8;
#pragma unroll
    for (int i = 0; i < 4; i++) qreg[i] = *(const short8*)(qp + 16 * i);
  }

  // all-ones bf16 B-frag for the denominator MFMA
  const unsigned one2 = 0x3F803F80u;
  const short8 ones = pack4(one2, one2, one2, one2);

  const f32x16 zz = {0.f, 0.f, 0.f, 0.f, 0.f, 0.f, 0.f, 0.f,
                     0.f, 0.f, 0.f, 0.f, 0.f, 0.f, 0.f, 0.f};
  f32x16 oA0 = zz, oA1 = zz, lA = zz;
  f32x16 oB0 = zz, oB1 = zz, lB = zz;

  // prologue: stage k-slab 0 (k 0..255) into buffer 0
#pragma unroll
  for (int i = 0; i < 4; i++) {
    const int db = (i * 512 + wq * 64) * 8;   // wave-uniform dest elem base
    gload_lds16(Kg + hbase + (size_t)kR[i] * 64 + kC[i] * 8, &Kl[0][db]);
    gload_lds16(Vg + hbase + (size_t)vR[i] * 2048 + vC[i] * 8, &Vl[0][db]);
  }
  __syncthreads();

  for (int it = 0; it < 8; ++it) {
    const int cur = it & 1;
    if (it < 7) {
      const int kt = (it + 1) * 256;
      const int nxt = cur ^ 1;
#pragma unroll
      for (int i = 0; i < 4; i++) {
        const int db = (i * 512 + wq * 64) * 8;
        gload_lds16(Kg + hbase + (size_t)(kt + kR[i]) * 64 + kC[i] * 8, &Kl[nxt][db]);
        gload_lds16(Vg + hbase + (size_t)vR[i] * 2048 + kt + vC[i] * 8, &Vl[nxt][db]);
      }
    }

#pragma unroll
    for (int hf = 0; hf < 2; hf++) {   // two 128-k compute phases per barrier
      const int koff = hf * 128;

      // QK^T over this 128-k half: 4 independent chains sc[t]
      f32x16 sc[4] = {zz, zz, zz, zz};
      __builtin_amdgcn_s_setprio(1);
#pragma unroll
      for (int i = 0; i < 4; i++) {
        const int c8 = 2 * i + hi;
#pragma unroll
        for (int t = 0; t < 4; t++) {
          const int r = koff + 32 * t + ql;
          short8 ka = *(const short8*)&Kl[cur][(r * 8 + (c8 ^ (r & 7))) * 8];
          sc[t] = __builtin_amdgcn_mfma_f32_32x32x16_bf16(ka, qreg[i], sc[t], 0, 0, 0);
        }
      }
      __builtin_amdgcn_s_setprio(0);

      // softmax (no-max: Q pre-scaled by log2e/8) + in-register P via permlane
      short8 pa[8];
#pragma unroll
      for (int t = 0; t < 4; t++) {
        float p[16];
#pragma unroll
        for (int r = 0; r < 16; r++) p[r] = __builtin_amdgcn_exp2f(sc[t][r]);
        unsigned w0a = cvtpk(p[0], p[1]),   w0b = cvtpk(p[2], p[3]);
        unsigned w1a = cvtpk(p[4], p[5]),   w1b = cvtpk(p[6], p[7]);
        unsigned w2a = cvtpk(p[8], p[9]),   w2b = cvtpk(p[10], p[11]);
        unsigned w3a = cvtpk(p[12], p[13]), w3b = cvtpk(p[14], p[15]);
        pl32(w0a, w1a);
        pl32(w0b, w1b);
        pa[2 * t] = pack4(w0a, w0b, w1a, w1b);
        pl32(w2a, w3a);
        pl32(w2b, w3b);
        pa[2 * t + 1] = pack4(w2a, w2b, w3a, w3b);
      }

      // PV over 8 k-slices of this half; even ks -> A-chains, odd -> B-chains
      __builtin_amdgcn_s_setprio(1);
#pragma unroll
      for (int ks = 0; ks < 8; ks += 2) {
        const int c8e = hf * 16 + 2 * ks + hi;
        const int c8o = hf * 16 + 2 * (ks + 1) + hi;
        const int r0 = ql, r1 = ql + 32;
        short8 ve0 = *(const short8*)&Vl[cur][(r0 * 32 + (c8e ^ (r0 & 31))) * 8];
        short8 ve1 = *(const short8*)&Vl[cur][(r1 * 32 + (c8e ^ (r1 & 31))) * 8];
        short8 vo0 = *(const short8*)&Vl[cur][(r0 * 32 + (c8o ^ (r0 & 31))) * 8];
        short8 vo1 = *(const short8*)&Vl[cur][(r1 * 32 + (c8o ^ (r1 & 31))) * 8];
        oA0 = __builtin_amdgcn_mfma_f32_32x32x16_bf16(pa[ks], ve0, oA0, 0, 0, 0);
        oA1 = __builtin_amdgcn_mfma_f32_32x32x16_bf16(pa[ks], ve1, oA1, 0, 0, 0);
        lA = __builtin_amdgcn_mfma_f32_32x32x16_bf16(pa[ks], ones, lA, 0, 0, 0);
        oB0 = __builtin_amdgcn_mfma_f32_32x32x16_bf16(pa[ks + 1], vo0, oB0, 0, 0, 0);
        oB1 = __builtin_amdgcn_mfma_f32_32x32x16_bf16(pa[ks + 1], vo1, oB1, 0, 0, 0);
        lB = __builtin_amdgcn_mfma_f32_32x32x16_bf16(pa[ks + 1], ones, lB, 0, 0, 0);
      }
      __builtin_amdgcn_s_setprio(0);
    }

    __syncthreads();  // next-slab loads landed + all waves done with cur
  }

  const int b = bh >> 3, h = bh & 7;
#pragma unroll
  for (int r = 0; r < 16; r++) {
    const int qrow = (r & 3) + 8 * (r >> 2) + 4 * hi;  // crow(r,hi) = q-local
    const float invr = 1.0f / (lA[r] + lB[r]);
    const size_t base = ((size_t)(b * 2048 + qw + qrow)) * 512 + h * 64 + ql;
    Og[base] = f2bf((oA0[r] + oB0[r]) * invr);
    Og[base + 32] = f2bf((oA1[r] + oB1[r]) * invr);
  }
}

// ---------------------------------------------------------------------------
// LayerNorm over last dim (512), one wave per token.
// ln_bf_k:   bf16 in -> bf16 out
// ln_bf2f_k: bf16 in -> fp32 out
// ---------------------------------------------------------------------------
__global__ __launch_bounds__(64) void ln_bf_k(const unsigned short* __restrict__ in,
                                              const float* __restrict__ g,
                                              const float* __restrict__ bb,
                                              unsigned short* __restrict__ out) {
  const int row = blockIdx.x, lane = threadIdx.x;
  ushort8 v = *(const ushort8*)(in + (size_t)row * 512 + lane * 8);
  float f[8];
#pragma unroll
  for (int j = 0; j < 8; j++) f[j] = bf2f(v[j]);
  float s = 0.f;
#pragma unroll
  for (int j = 0; j < 8; j++) s += f[j];
#pragma unroll
  for (int off = 32; off >= 1; off >>= 1) s += __shfl_xor(s, off);
  const float mu = s * (1.f / 512.f);
  float q = 0.f;
#pragma unroll
  for (int j = 0; j < 8; j++) { const float d = f[j] - mu; q += d * d; }
#pragma unroll
  for (int off = 32; off >= 1; off >>= 1) q += __shfl_xor(q, off);
  const float rstd = rsqrtf(q * (1.f / 512.f) + 1e-5f);
  const float4* gp = (const float4*)g;
  const float4* bp = (const float4*)bb;
  float4 g0 = gp[lane * 2], g1 = gp[lane * 2 + 1];
  float4 c0 = bp[lane * 2], c1 = bp[lane * 2 + 1];
  const float gg[8] = {g0.x, g0.y, g0.z, g0.w, g1.x, g1.y, g1.z, g1.w};
  const float cc[8] = {c0.x, c0.y, c0.z, c0.w, c1.x, c1.y, c1.z, c1.w};
  ushort8 ov;
#pragma unroll
  for (int j = 0; j < 8; j++) ov[j] = f2bf((f[j] - mu) * rstd * gg[j] + cc[j]);
  *(ushort8*)(out + (size_t)row * 512 + lane * 8) = ov;
}

__global__ __launch_bounds__(64) void ln_bf2f_k(const unsigned short* __restrict__ in,
                                                const float* __restrict__ g,
                                                const float* __restrict__ bb,
                                                float* __restrict__ outf) {
  const int row = blockIdx.x, lane = threadIdx.x;
  ushort8 v = *(const ushort8*)(in + (size_t)row * 512 + lane * 8);
  float f[8];
#pragma unroll
  for (int j = 0; j < 8; j++) f[j] = bf2f(v[j]);
  float s = 0.f;
#pragma unroll
  for (int j = 0; j < 8; j++) s += f[j];
#pragma unroll
  for (int off = 32; off >= 1; off >>= 1) s += __shfl_xor(s, off);
  const float mu = s * (1.f / 512.f);
  float q = 0.f;
#pragma unroll
  for (int j = 0; j < 8; j++) { const float d = f[j] - mu; q += d * d; }
#pragma unroll
  for (int off = 32; off >= 1; off >>= 1) q += __shfl_xor(q, off);
  const float rstd = rsqrtf(q * (1.f / 512.f) + 1e-5f);
  const float4* gp = (const float4*)g;
  const float4* bp = (const float4*)bb;
  float4 g0 = gp[lane * 2], g1 = gp[lane * 2 + 1];
  float4 c0 = bp[lane * 2], c1 = bp[lane * 2 + 1];
  const float gg[8] = {g0.x, g0.y, g0.z, g0.w, g1.x, g1.y, g1.z, g1.w};
  const float cc[8] = {c0.x, c0.y, c0.z, c0.w, c1.x, c1.y, c1.z, c1.w};
  float4 o0, o1;
  float* o0p = &o0.x;
  float* o1p = &o1.x;
#pragma unroll
  for (int j = 0; j < 4; j++) o0p[j] = (f[j] - mu) * rstd * gg[j] + cc[j];
#pragma unroll
  for (int j = 0; j < 4; j++) o1p[j] = (f[j + 4] - mu) * rstd * gg[j + 4] + cc[j + 4];
  float4* of = (float4*)(outf + (size_t)row * 512 + lane * 8);
  of[0] = o0;
  of[1] = o1;
}

// ---------------------------------------------------------------------------
extern "C" void kernel_launch(void* const* d_in, const int* in_sizes, int n_in,
                              void* d_out, int out_size, void* d_ws, size_t ws_size,
                              hipStream_t stream) {
  const float* x = (const float*)d_in[0];
  const float* wq = (const float*)d_in[1];
  const float* bq = (const float*)d_in[2];
  const float* wk = (const float*)d_in[3];
  const float* bk = (const float*)d_in[4];
  const float* wv = (const float*)d_in[5];
  const float* bv = (const float*)d_in[6];
  const float* wo = (const float*)d_in[7];
  const float* bo = (const float*)d_in[8];
  const float* ln_g = (const float*)d_in[9];
  const float* ln_b = (const float*)d_in[10];
  const float* w1 = (const float*)d_in[11];
  const float* b1 = (const float*)d_in[12];
  const float* w2 = (const float*)d_in[13];
  const float* b2 = (const float*)d_in[14];

  // workspace carve-up (ushort elems)
  unsigned short* ws_u = (unsigned short*)d_ws;
  unsigned short* wqkv = ws_u;                   // 786432
  unsigned short* wob = wqkv + 786432;           // 262144
  unsigned short* w1b = wob + 262144;            // 1048576
  unsigned short* w2b = w1b + 1048576;           // 1048576
  unsigned short* xb = w2b + 1048576;            // 4194304  [8192][512]
  unsigned short* qb = xb + 4194304;             // [32][2048][64]
  unsigned short* kb = qb + 4194304;             // [32][2048][64]
  unsigned short* vtb = kb + 4194304;            // V^T [32][64][2048]
  unsigned short* ob = vtb + 4194304;            // attn out [8192][512]
  unsigned short* s1b = ob + 4194304;            // h_pre bf16 / y2 bf16 [8192][512]
  unsigned short* hb = s1b + 4194304;            // h bf16 [8192][512]
  unsigned short* f1b = qb;                      // reuse qb..ob: [8192][2048]
  float* bqkv = (float*)(hb + 4194304);          // 1536

  // one fused convert+bias launch for all weights + x
  cvt_all_k<<<7169, 256, 0, stream>>>(
      (const float4*)wq, (const float4*)wk, (const float4*)wv, (const float4*)wo,
      (const float4*)w1, (const float4*)w2, (const float4*)x,
      (ushort4v*)wqkv, (ushort4v*)wob, (ushort4v*)w1b, (ushort4v*)w2b,
      (ushort4v*)xb, bq, bk, bv, bqkv);

  // QKV projection: M=8192, N=1536, K=512 -> scatter into qb/kb/vtb
  gemm_bt<0><<<dim3(64, 12), 256, 0, stream>>>(xb, wqkv, bqkv, 8192, 1536, 512,
                                               qb, nullptr, nullptr);
  // attention (256 blocks x 512 threads, XCD-chunked internally)
  attn_k<<<256, 512, 0, stream>>>(qb, kb, vtb, ob);
  // O projection + residual(xb): -> s1b bf16   (128x64 tiles, BK=128)
  gemm_n64<1><<<dim3(64, 8), 256, 0, stream>>>(ob, wob, bo, 8192, 512, 512,
                                               s1b, nullptr, xb);
  // LN1 (bf16 -> bf16)
  ln_bf_k<<<8192, 64, 0, stream>>>(s1b, ln_g, ln_b, hb);
  // FFN1 + ReLU: M=8192, N=2048, K=512 -> f1b bf16 (256x128 tiles, 8 waves)
  gemm_ffn1<<<dim3(32, 16), 512, 0, stream>>>(hb, w1b, b1, 8192, 2048, 512, f1b);
  // FFN2 + residual(hb): M=8192, N=512, K=2048 -> s1b bf16 (BK=128)
  gemm_n64<1><<<dim3(64, 8), 256, 0, stream>>>(f1b, w2b, b2, 8192, 512, 2048,
                                               s1b, nullptr, hb);
  // LN2: bf16 in -> fp32 d_out
  ln_bf2f_k<<<8192, 64, 0, stream>>>(s1b, ln_g, ln_b, (float*)d_out);
}